// Round 9
// baseline (199958.875 us; speedup 1.0000x reference)
//
#include <hip/hip_runtime.h>
#include <cmath>

#define LL 6
#define NTOT 4194304
#define R0Q 3145727ULL   // 0-indexed rank: 0.75*(NTOT-1)=3145727.25 -> i=3145727, gamma=0.25

// ---------------------------------------------------------------------------
// numpy pairwise summation for n=512, contiguous f32, as ACTUALLY compiled in
// numpy >=1.21 wheels: FLOAT_pairwise_sum's NPY_SIMD base case at wheel
// baseline (SSE3, vl=4). For each 128-block: 8 npyv regs r0..r7 (32 chains,
// chain c accumulates a[c], a[c+32], a[c+64], a[c+96] sequentially), combine
// ((r0+r1)+(r2+r3))+((r4+r5)+(r6+r7)) vec-wise (chain-distance 4,8,16), then
// SSE3 hadd,hadd lane tree (T0+T1)+(T2+T3) (distance 1,2). 512 recurses
// 256+256 -> four 128-blocks combined ((B0+B1)+(B2+B3)). IEEE add commutes,
// so xor-shuffle trees are bit-exact.
__device__ __forceinline__ float pairwise512(const float* a, int lane) {
    float B0, B1, B2, B3;
    #pragma unroll
    for (int b = 0; b < 4; b++) {
        float s = 0.0f;
        if (lane < 32) {
            const float* p = a + b * 128 + lane;
            s = __fadd_rn(__fadd_rn(__fadd_rn(p[0], p[32]), p[64]), p[96]);
        }
        s = __fadd_rn(s, __shfl_xor(s, 4, 64));    // r0+r1 / r2+r3 / r4+r5 / r6+r7
        s = __fadd_rn(s, __shfl_xor(s, 8, 64));    // (r0+r1)+(r2+r3) / (r4+r5)+(r6+r7)
        s = __fadd_rn(s, __shfl_xor(s, 16, 64));   // full reg combine
        s = __fadd_rn(s, __shfl_xor(s, 1, 64));    // hadd: T0+T1 / T2+T3
        s = __fadd_rn(s, __shfl_xor(s, 2, 64));    // (T0+T1)+(T2+T3)
        float bs = __shfl(s, 0, 64);
        if (b == 0) B0 = bs; else if (b == 1) B1 = bs; else if (b == 2) B2 = bs; else B3 = bs;
    }
    return __fadd_rn(__fadd_rn(B0, B1), __fadd_rn(B2, B3));
}

// numpy f32 SIMD exp (FMA path, Cephes constants): rint + Cody-Waite + Horner.
__device__ __forceinline__ float np_expf(float x) {
    float q = rintf(__fmul_rn(x, 1.44269504088896341f));
    float r = __builtin_fmaf(q, -0.693359375f, x);
    r = __builtin_fmaf(q, 2.12194440e-4f, r);
    float p = 1.9875691500e-4f;
    p = __builtin_fmaf(p, r, 1.3981999507e-3f);
    p = __builtin_fmaf(p, r, 8.3334519073e-3f);
    p = __builtin_fmaf(p, r, 4.1665795894e-2f);
    p = __builtin_fmaf(p, r, 1.6666665459e-1f);
    p = __builtin_fmaf(p, r, 5.0000001201e-1f);
    float r2 = __fmul_rn(r, r);
    p = __builtin_fmaf(p, r2, r);
    p = __fadd_rn(p, 1.0f);
    int qi = (int)q;
    float sc;
    if (qi >= -126) sc = __uint_as_float((unsigned)((qi + 127) << 23));
    else { sc = __uint_as_float((unsigned)((qi + 127 + 64) << 23));
           sc = __fmul_rn(sc, __uint_as_float((unsigned)((127 - 64) << 23))); }
    return __fmul_rn(p, sc);
}

// ---------------- embedding: x = emb[src]*sc + pos (f32 ops) ----------------
__global__ __launch_bounds__(256) void k_embed32(const int* __restrict__ src,
                                                 const float* __restrict__ emb,
                                                 const float* __restrict__ pos,
                                                 float* __restrict__ x, float sc) {
    int idx = blockIdx.x * 256 + threadIdx.x;
    int row = idx >> 9, d = idx & 511, s = row & 511;
    int tok = src[row];
    x[idx] = __fadd_rn(__fmul_rn(emb[(size_t)tok * 512 + d], sc), pos[(size_t)s * 512 + d]);
}

// ---------------- f32 GEMM: C = A[M,K] @ W[N,K]^T (+bias)(+relu) ------------
// Sequential-k fma chain with OpenBLAS level3.c K-blocking:
//   K=512 -> [256,256]; K=2048 -> [384x4,256,256].
__global__ __launch_bounds__(256) void k_gemm_seq(const float* __restrict__ A,
                                                  const float* __restrict__ W,
                                                  const float* __restrict__ bias,
                                                  float* __restrict__ C,
                                                  int N, int K, int flags) { // 1=bias, 2=relu
    __shared__ float As[16][65];
    __shared__ float Ws[16][65];
    int t = threadIdx.x;
    int tm = t & 15, tn = t >> 4;
    int row0 = blockIdx.y * 64, col0 = blockIdx.x * 64;
    int lm = t >> 2, lk = (t & 3) * 4;
    float acc[4][4] = {}, cmem[4][4] = {};
    for (int k0 = 0; k0 < K; k0 += 16) {
        const float* Ap = A + (size_t)(row0 + lm) * K + k0 + lk;
        #pragma unroll
        for (int i = 0; i < 4; i++) As[lk + i][lm] = Ap[i];
        int wr = col0 + lm;
        const float* Wp = W + (size_t)wr * K + k0 + lk;
        #pragma unroll
        for (int i = 0; i < 4; i++) Ws[lk + i][lm] = (wr < N) ? Wp[i] : 0.0f;
        __syncthreads();
        #pragma unroll
        for (int kk = 0; kk < 16; kk++) {
            float a[4], b[4];
            #pragma unroll
            for (int i = 0; i < 4; i++) a[i] = As[kk][tm + 16 * i];
            #pragma unroll
            for (int j = 0; j < 4; j++) b[j] = Ws[kk][tn + 16 * j];
            #pragma unroll
            for (int i = 0; i < 4; i++)
                #pragma unroll
                for (int j = 0; j < 4; j++)
                    acc[i][j] = __builtin_fmaf(a[i], b[j], acc[i][j]);
        }
        __syncthreads();
        int ke = k0 + 16;
        bool fold = (K == 512) ? (ke == 256)
                  : ((ke <= 1536 && (ke % 384) == 0) || ke == 1792);
        if (fold && ke < K) {
            #pragma unroll
            for (int i = 0; i < 4; i++)
                #pragma unroll
                for (int j = 0; j < 4; j++) {
                    cmem[i][j] = __fadd_rn(cmem[i][j], acc[i][j]);
                    acc[i][j] = 0.0f;
                }
        }
    }
    #pragma unroll
    for (int i = 0; i < 4; i++)
        #pragma unroll
        for (int j = 0; j < 4; j++) {
            int r = row0 + tm + 16 * i, c = col0 + tn + 16 * j;
            if (c < N) {
                float v = __fadd_rn(cmem[i][j], acc[i][j]);
                if (flags & 1) v = __fadd_rn(v, bias[c]);
                if (flags & 2) v = fmaxf(v, 0.0f);
                C[(size_t)r * N + c] = v;
            }
        }
}

// ---------------- attention scores (np.einsum SSE baseline dot) -------------
__global__ __launch_bounds__(256) void k_scores(const float* __restrict__ qkv,
                                                float* __restrict__ attnP, int b0) {
    __shared__ float qs[4][64];
    int wid = threadIdx.x >> 6, lane = threadIdx.x & 63;
    int bx = blockIdx.x;
    int q4 = bx & 127, h = (bx >> 7) & 7, bi = bx >> 10;
    int b = b0 + bi;
    int q = q4 * 4 + wid;
    qs[wid][lane] = qkv[(size_t)(b * 512 + q) * 1536 + h * 64 + lane];
    __syncthreads();
    const float* qv = qs[wid];
    float out[8];
    for (int i = 0; i < 8; i++) {
        int k = i * 64 + lane;
        const float* kr = qkv + (size_t)(b * 512 + k) * 1536 + 512 + h * 64;
        float a0 = 0.f, a1 = 0.f, a2 = 0.f, a3 = 0.f;
        #pragma unroll
        for (int d = 0; d < 64; d += 4) {
            a0 = __fadd_rn(a0, __fmul_rn(qv[d + 0], kr[d + 0]));
            a1 = __fadd_rn(a1, __fmul_rn(qv[d + 1], kr[d + 1]));
            a2 = __fadd_rn(a2, __fmul_rn(qv[d + 2], kr[d + 2]));
            a3 = __fadd_rn(a3, __fmul_rn(qv[d + 3], kr[d + 3]));
        }
        float s = __fadd_rn(__fadd_rn(a0, a1), __fadd_rn(a2, a3));
        out[i] = __fmul_rn(s, 0.125f);
    }
    float* orow = attnP + ((size_t)(bi * 8 + h) * 512 + q) * 512;
    for (int i = 0; i < 8; i++) orow[i * 64 + lane] = out[i];
}

// ---------------- softmax rows (exact max, np_expf, np pairwise sum) --------
__global__ __launch_bounds__(256) void k_softmax(float* __restrict__ attnP) {
    __shared__ float ebuf[4][512];
    int wid = threadIdx.x >> 6, lane = threadIdx.x & 63;
    int row = blockIdx.x * 4 + wid;
    float* pr = attnP + (size_t)row * 512;
    float s[8], m = -INFINITY;
    for (int i = 0; i < 8; i++) { s[i] = pr[i * 64 + lane]; m = fmaxf(m, s[i]); }
    for (int off = 32; off; off >>= 1) m = fmaxf(m, __shfl_xor(m, off, 64));
    for (int i = 0; i < 8; i++)
        ebuf[wid][i * 64 + lane] = np_expf(__fsub_rn(s[i], m));
    __syncthreads();
    float sum = pairwise512(ebuf[wid], lane);
    for (int i = 0; i < 8; i++) pr[i * 64 + lane] = __fdiv_rn(ebuf[wid][i * 64 + lane], sum);
}

// ---------------- PV einsum: sequential k, scalar mul+add (no fma) ----------
__global__ __launch_bounds__(256) void k_pv(const float* __restrict__ attnP,
                                            const float* __restrict__ qkv,
                                            float* __restrict__ ctx, int b0) {
    __shared__ float at_s[64][65];
    __shared__ float v_s[64][65];
    int t = threadIdx.x;
    int bx = blockIdx.x;
    int qt = bx & 7, h = (bx >> 3) & 7, bi = bx >> 6;
    int b = b0 + bi;
    int tm = t & 15, tn = t >> 4;
    int lr = t >> 2, lc = (t & 3) * 16;
    float acc[4][4] = {};
    for (int c = 0; c < 8; c++) {
        const float* ar = attnP + ((size_t)(bi * 8 + h) * 512 + qt * 64 + lr) * 512 + c * 64 + lc;
        #pragma unroll
        for (int i = 0; i < 16; i++) at_s[lr][lc + i] = ar[i];
        const float* vr = qkv + (size_t)(b * 512 + c * 64 + lr) * 1536 + 1024 + h * 64 + lc;
        #pragma unroll
        for (int i = 0; i < 16; i++) v_s[lr][lc + i] = vr[i];
        __syncthreads();
        #pragma unroll
        for (int kk = 0; kk < 64; kk++) {
            float av[4], bv[4];
            #pragma unroll
            for (int i = 0; i < 4; i++) av[i] = at_s[tm + 16 * i][kk];
            #pragma unroll
            for (int j = 0; j < 4; j++) bv[j] = v_s[kk][tn + 16 * j];
            #pragma unroll
            for (int i = 0; i < 4; i++)
                #pragma unroll
                for (int j = 0; j < 4; j++)
                    acc[i][j] = __fadd_rn(acc[i][j], __fmul_rn(av[i], bv[j]));
        }
        __syncthreads();
    }
    #pragma unroll
    for (int i = 0; i < 4; i++)
        #pragma unroll
        for (int j = 0; j < 4; j++) {
            int q = qt * 64 + tm + 16 * i, dh = tn + 16 * j;
            ctx[(size_t)(b * 512 + q) * 512 + h * 64 + dh] = acc[i][j];
        }
}

// ---------------- residual + LayerNorm (numpy order, pairwise trees) --------
__global__ __launch_bounds__(256) void k_addln32(const float* __restrict__ xin,
                                                 const float* __restrict__ yin,
                                                 const float* __restrict__ ob,
                                                 const float* __restrict__ sc,
                                                 const float* __restrict__ bi,
                                                 float* __restrict__ xout) {
    __shared__ float buf[512];
    __shared__ float d2[512];
    __shared__ float stats[2];
    int row = blockIdx.x, t = threadIdx.x;
    const float* xr = xin + (size_t)row * 512;
    const float* yr = yin + (size_t)row * 512;
    float v0 = __fadd_rn(xr[t], yr[t]);
    float v1 = __fadd_rn(xr[t + 256], yr[t + 256]);
    if (ob) { v0 = __fadd_rn(v0, ob[t]); v1 = __fadd_rn(v1, ob[t + 256]); }
    buf[t] = v0; buf[t + 256] = v1;
    __syncthreads();
    int lane = t & 63;
    if (t < 64) {
        float s = pairwise512(buf, lane);
        if (lane == 0) stats[0] = __fdiv_rn(s, 512.0f);
    }
    __syncthreads();
    float mean = stats[0];
    float d0 = __fsub_rn(v0, mean), d1 = __fsub_rn(v1, mean);
    d2[t] = __fmul_rn(d0, d0); d2[t + 256] = __fmul_rn(d1, d1);
    __syncthreads();
    if (t < 64) {
        float s = pairwise512(d2, lane);
        if (lane == 0) {
            float var = __fdiv_rn(s, 512.0f);
            stats[1] = __fdiv_rn(1.0f, __fsqrt_rn(__fadd_rn(var, 1e-5f)));
        }
    }
    __syncthreads();
    float inv = stats[1];
    xout[(size_t)row * 512 + t]       = __fadd_rn(__fmul_rn(__fmul_rn(d0, inv), sc[t]), bi[t]);
    xout[(size_t)row * 512 + t + 256] = __fadd_rn(__fmul_rn(__fmul_rn(d1, inv), sc[t + 256]), bi[t + 256]);
}

// ---------------- norm denominator (set-invariant: |g| ordering == |x|) -----
__global__ void k_sdot(const float* __restrict__ x, float* __restrict__ den) {
    int c = threadIdx.x;
    float acc = 0.0f;
    if (c < 32) {
        for (int i = c; i < NTOT; i += 32)
            acc = __builtin_fmaf(x[i], x[i], acc);
    }
    acc = __fadd_rn(acc, __shfl_xor(acc, 8, 64));
    acc = __fadd_rn(acc, __shfl_xor(acc, 16, 64));
    acc = __fadd_rn(acc, __shfl_xor(acc, 4, 64));
    acc = __fadd_rn(acc, __shfl_xor(acc, 1, 64));
    acc = __fadd_rn(acc, __shfl_xor(acc, 2, 64));
    if (c == 0) den[0] = __fadd_rn(__fsqrt_rn(acc), 1e-8f);
}

// ---------------- quantile machinery (32-bit radix select on f32 keys) ------
__global__ void k_qinit(unsigned long long* state, unsigned int* hist) {
    int t = threadIdx.x;
    hist[t] = 0;
    if (t == 0) { state[0] = 0; state[1] = R0Q; state[2] = 0; state[3] = ~0ULL; }
}

__global__ __launch_bounds__(256) void k_gkeys32(const float* __restrict__ x,
                                                 const float* __restrict__ den_p,
                                                 unsigned int* __restrict__ keys) {
    int i = blockIdx.x * 256 + threadIdx.x;
    float g = __fmul_rn(__fdiv_rn(x[i], den_p[0]), 2048.0f);
    keys[i] = __float_as_uint(fabsf(g));
}

__global__ __launch_bounds__(256) void k_hist32(const unsigned int* __restrict__ keys,
                                                const unsigned long long* __restrict__ state,
                                                unsigned int* __restrict__ hist, int shift) {
    __shared__ unsigned int h[256];
    h[threadIdx.x] = 0;
    __syncthreads();
    unsigned int pref = (unsigned int)state[0];
    for (size_t i = (size_t)blockIdx.x * 256 + threadIdx.x; i < (size_t)NTOT; i += 262144) {
        unsigned int k = keys[i];
        if (shift == 24 || (k >> (shift + 8)) == pref)
            atomicAdd(&h[(k >> shift) & 255u], 1u);
    }
    __syncthreads();
    atomicAdd(&hist[threadIdx.x], h[threadIdx.x]);
}

__global__ void k_scan32(unsigned long long* state, unsigned int* hist) {
    if (threadIdx.x == 0) {
        unsigned long long r = state[1], cum = 0;
        int b = 0;
        for (; b < 256; b++) {
            unsigned long long c = hist[b];
            if (cum + c > r) break;
            cum += c;
        }
        state[0] = (state[0] << 8) | (unsigned long long)b;
        state[1] = r - cum;
    }
    __syncthreads();
    hist[threadIdx.x] = 0;
}

__global__ __launch_bounds__(256) void k_fixcnt32(const unsigned int* __restrict__ keys,
                                                  unsigned long long* __restrict__ state) {
    __shared__ unsigned long long lc[4];
    __shared__ unsigned int lm[4];
    unsigned int v0 = (unsigned int)state[0];
    unsigned long long cnt = 0;
    unsigned int mn = 0xFFFFFFFFu;
    for (size_t i = (size_t)blockIdx.x * 256 + threadIdx.x; i < (size_t)NTOT; i += 262144) {
        unsigned int k = keys[i];
        if (k <= v0) cnt++;
        else if (k < mn) mn = k;
    }
    for (int off = 32; off; off >>= 1) {
        cnt += __shfl_xor(cnt, off, 64);
        unsigned int o = __shfl_xor(mn, off, 64);
        if (o < mn) mn = o;
    }
    int wid = threadIdx.x >> 6, ln = threadIdx.x & 63;
    if (ln == 0) { lc[wid] = cnt; lm[wid] = mn; }
    __syncthreads();
    if (threadIdx.x == 0) {
        unsigned long long c = lc[0] + lc[1] + lc[2] + lc[3];
        unsigned int m2 = lm[0];
        if (lm[1] < m2) m2 = lm[1];
        if (lm[2] < m2) m2 = lm[2];
        if (lm[3] < m2) m2 = lm[3];
        atomicAdd(&state[2], c);
        atomicMin(&state[3], (unsigned long long)m2);
    }
}

// canonical numpy lerp threshold (all layers)
__global__ void k_thr32(const unsigned long long* __restrict__ state,
                        float* __restrict__ thr_p) {
    if (threadIdx.x == 0 && blockIdx.x == 0) {
        float a = __uint_as_float((unsigned int)state[0]);
        float b = (state[2] > R0Q + 1) ? a : __uint_as_float((unsigned int)state[3]);
        thr_p[0] = __fadd_rn(a, __fmul_rn(__fsub_rn(b, a), 0.25f));
    }
}

__global__ __launch_bounds__(256) void k_damp32(float* __restrict__ x,
                                                const float* __restrict__ den_p,
                                                const float* __restrict__ thr_p,
                                                float c1, float c2) {
    int i = blockIdx.x * 256 + threadIdx.x;
    float g = __fmul_rn(__fdiv_rn(x[i], den_p[0]), 2048.0f);
    float v = (fabsf(g) > thr_p[0]) ? g : 0.0f;
    x[i] = __fmul_rn(__fmul_rn(v, c1), c2);
}

// ---------------- host orchestration ----------------------------------------
extern "C" void kernel_launch(void* const* d_in, const int* in_sizes, int n_in,
                              void* d_out, int out_size, void* d_ws, size_t ws_size,
                              hipStream_t stream) {
    const int*   src     = (const int*)d_in[0];
    const float* emb     = (const float*)d_in[1];
    const float* pos     = (const float*)d_in[2];
    const float* qkv_w   = (const float*)d_in[3];
    const float* qkv_b   = (const float*)d_in[4];
    const float* attn_ow = (const float*)d_in[5];
    const float* attn_ob = (const float*)d_in[6];
    const float* ln1_s   = (const float*)d_in[7];
    const float* ln1_b   = (const float*)d_in[8];
    const float* ln2_s   = (const float*)d_in[9];
    const float* ln2_b   = (const float*)d_in[10];
    const float* ff1_w   = (const float*)d_in[11];
    const float* ff1_b   = (const float*)d_in[12];
    const float* ff2_w   = (const float*)d_in[13];
    const float* ff2_b   = (const float*)d_in[14];
    const float* head_w  = (const float*)d_in[15];
    const float* head_b  = (const float*)d_in[16];

    char* ws = (char*)d_ws;
    float* x    = (float*)(ws + 0);
    float* qkv  = (float*)(ws + 16777216ULL);
    float* ffh  = (float*)(ws + 67108864ULL);
    float* y    = (float*)(ws + 134217728ULL);
    float* ctx  = (float*)(ws + 150994944ULL);
    float* attnP= (float*)(ws + 167772160ULL);
    unsigned int* keys = (unsigned int*)ctx;            // aliases ctx (dead by then)
    float*  den  = (float*)(ws + 184557568ULL);
    float*  thr  = (float*)(ws + 184557572ULL);
    unsigned int* hist = (unsigned int*)(ws + 184561664ULL);
    unsigned long long* state = (unsigned long long*)(ws + 184565760ULL);

    float sc_emb = (float)sqrt(512.0);                 // np.sqrt(D).astype(f32)
    float c1 = (float)pow(0.99, 1.0 / 6.0);            // np.float32(DAMP**(1/L))

    k_embed32<<<16384, 256, 0, stream>>>(src, emb, pos, x, sc_emb);

    for (int l = 0; l < LL; l++) {
        // qkv = x @ qkv_w^T + qkv_b
        k_gemm_seq<<<dim3(24, 128), 256, 0, stream>>>(
            x, qkv_w + (size_t)l * 1536 * 512, qkv_b + (size_t)l * 1536, qkv, 1536, 512, 1);
        // attention, 2 batches per phase
        for (int ph = 0; ph < 8; ph++) {
            int b0 = ph * 2;
            k_scores<<<2048, 256, 0, stream>>>(qkv, attnP, b0);
            k_softmax<<<2048, 256, 0, stream>>>(attnP);
            k_pv<<<128, 256, 0, stream>>>(attnP, qkv, ctx, b0);
        }
        // proj (raw matmul; ob added in addln to match ((x + mm) + ob) order)
        k_gemm_seq<<<dim3(8, 128), 256, 0, stream>>>(
            ctx, attn_ow + (size_t)l * 512 * 512, nullptr, y, 512, 512, 0);
        k_addln32<<<8192, 256, 0, stream>>>(x, y, attn_ob + (size_t)l * 512,
                                            ln1_s + (size_t)l * 512, ln1_b + (size_t)l * 512, x);
        // FF
        k_gemm_seq<<<dim3(32, 128), 256, 0, stream>>>(
            x, ff1_w + (size_t)l * 2048 * 512, ff1_b + (size_t)l * 2048, ffh, 2048, 512, 3);
        k_gemm_seq<<<dim3(8, 128), 256, 0, stream>>>(
            ffh, ff2_w + (size_t)l * 512 * 2048, ff2_b + (size_t)l * 512, y, 512, 2048, 1);
        k_addln32<<<8192, 256, 0, stream>>>(x, y, nullptr,
                                            ln2_s + (size_t)l * 512, ln2_b + (size_t)l * 512, x);
        // resonance: norm (set-invariant), radix-select quantile, threshold+damp
        k_sdot<<<1, 64, 0, stream>>>(x, den);
        k_qinit<<<1, 256, 0, stream>>>(state, hist);
        k_gkeys32<<<16384, 256, 0, stream>>>(x, den, keys);
        for (int p = 0; p < 4; p++) {
            k_hist32<<<1024, 256, 0, stream>>>(keys, state, hist, 24 - 8 * p);
            k_scan32<<<1, 256, 0, stream>>>(state, hist);
        }
        k_fixcnt32<<<1024, 256, 0, stream>>>(keys, state);
        k_thr32<<<1, 1, 0, stream>>>(state, thr);
        float c2 = (float)pow(0.99, (double)l / 6.0);  // np.float32(DAMP**(i/L))
        k_damp32<<<16384, 256, 0, stream>>>(x, den, thr, c1, c2);
    }

    // head: out = x @ head_w^T + head_b
    k_gemm_seq<<<dim3(157, 128), 256, 0, stream>>>(
        x, head_w, head_b, (float*)d_out, 10000, 512, 1);
}

// Round 10
// 18121.851 us; speedup vs baseline: 11.0341x; 11.0341x over previous
//
#include <hip/hip_runtime.h>
#include <cmath>

#define LL 6
#define NTOT 4194304
#define R0Q 3145727ULL   // 0-indexed rank: 0.75*(NTOT-1)=3145727.25 -> i=3145727, gamma=0.25

// ---------------------------------------------------------------------------
// numpy pairwise summation for n=512 (C3 SIMD variant, verified bit-exact in R9).
__device__ __forceinline__ float pairwise512(const float* a, int lane) {
    float B0, B1, B2, B3;
    #pragma unroll
    for (int b = 0; b < 4; b++) {
        float s = 0.0f;
        if (lane < 32) {
            const float* p = a + b * 128 + lane;
            s = __fadd_rn(__fadd_rn(__fadd_rn(p[0], p[32]), p[64]), p[96]);
        }
        s = __fadd_rn(s, __shfl_xor(s, 4, 64));
        s = __fadd_rn(s, __shfl_xor(s, 8, 64));
        s = __fadd_rn(s, __shfl_xor(s, 16, 64));
        s = __fadd_rn(s, __shfl_xor(s, 1, 64));
        s = __fadd_rn(s, __shfl_xor(s, 2, 64));
        float bs = __shfl(s, 0, 64);
        if (b == 0) B0 = bs; else if (b == 1) B1 = bs; else if (b == 2) B2 = bs; else B3 = bs;
    }
    return __fadd_rn(__fadd_rn(B0, B1), __fadd_rn(B2, B3));
}

// numpy f32 SIMD exp (FMA path, Cephes constants) — verified bit-exact in R9.
__device__ __forceinline__ float np_expf(float x) {
    float q = rintf(__fmul_rn(x, 1.44269504088896341f));
    float r = __builtin_fmaf(q, -0.693359375f, x);
    r = __builtin_fmaf(q, 2.12194440e-4f, r);
    float p = 1.9875691500e-4f;
    p = __builtin_fmaf(p, r, 1.3981999507e-3f);
    p = __builtin_fmaf(p, r, 8.3334519073e-3f);
    p = __builtin_fmaf(p, r, 4.1665795894e-2f);
    p = __builtin_fmaf(p, r, 1.6666665459e-1f);
    p = __builtin_fmaf(p, r, 5.0000001201e-1f);
    float r2 = __fmul_rn(r, r);
    p = __builtin_fmaf(p, r2, r);
    p = __fadd_rn(p, 1.0f);
    int qi = (int)q;
    float sc;
    if (qi >= -126) sc = __uint_as_float((unsigned)((qi + 127) << 23));
    else { sc = __uint_as_float((unsigned)((qi + 127 + 64) << 23));
           sc = __fmul_rn(sc, __uint_as_float((unsigned)((127 - 64) << 23))); }
    return __fmul_rn(p, sc);
}

// ---------------- embedding (unchanged) ----------------
__global__ __launch_bounds__(256) void k_embed32(const int* __restrict__ src,
                                                 const float* __restrict__ emb,
                                                 const float* __restrict__ pos,
                                                 float* __restrict__ x, float sc) {
    int idx = blockIdx.x * 256 + threadIdx.x;
    int row = idx >> 9, d = idx & 511, s = row & 511;
    int tok = src[row];
    x[idx] = __fadd_rn(__fmul_rn(emb[(size_t)tok * 512 + d], sc), pos[(size_t)s * 512 + d]);
}

// ---------------- f32 GEMM v2: 128x64 tile, 8x4/thread, b128 LDS reads ------
// Per-element arithmetic IDENTICAL to R9: sequential-k fma chain over BK=16
// tiles ascending, OpenBLAS fold points (K=512 -> fold@256; K=2048 ->
// folds@384,768,1152,1536,1792), final (cmem+acc)+bias, relu.
__global__ __launch_bounds__(256) void k_gemm2(const float* __restrict__ A,
                                               const float* __restrict__ W,
                                               const float* __restrict__ bias,
                                               float* __restrict__ C,
                                               int N, int K, int flags) { // 1=bias, 2=relu
    __shared__ float As[16][128];   // [kk][row]
    __shared__ float Ws[16][64];    // [kk][col]
    int t = threadIdx.x;
    int tm = t & 15, tn = t >> 4;
    int row0 = blockIdx.y * 128, col0 = blockIdx.x * 64;
    int ra = t >> 1, ka = (t & 1) * 8;
    int wc = t >> 2, kw = (t & 3) * 4;
    float acc[8][4] = {}, cmem[8][4] = {};
    for (int k0 = 0; k0 < K; k0 += 16) {
        const float* Ap = A + (size_t)(row0 + ra) * K + k0 + ka;
        float4 a0 = *(const float4*)Ap;
        float4 a1 = *(const float4*)(Ap + 4);
        As[ka + 0][ra] = a0.x; As[ka + 1][ra] = a0.y; As[ka + 2][ra] = a0.z; As[ka + 3][ra] = a0.w;
        As[ka + 4][ra] = a1.x; As[ka + 5][ra] = a1.y; As[ka + 6][ra] = a1.z; As[ka + 7][ra] = a1.w;
        int wr = col0 + wc;
        float4 w0 = make_float4(0.f, 0.f, 0.f, 0.f);
        if (wr < N) w0 = *(const float4*)(W + (size_t)wr * K + k0 + kw);
        Ws[kw + 0][wc] = w0.x; Ws[kw + 1][wc] = w0.y; Ws[kw + 2][wc] = w0.z; Ws[kw + 3][wc] = w0.w;
        __syncthreads();
        #pragma unroll
        for (int kk = 0; kk < 16; kk++) {
            float4 va = *(const float4*)&As[kk][tm * 4];
            float4 vb = *(const float4*)&As[kk][64 + tm * 4];
            float4 wv = *(const float4*)&Ws[kk][tn * 4];
            float a[8] = {va.x, va.y, va.z, va.w, vb.x, vb.y, vb.z, vb.w};
            float w[4] = {wv.x, wv.y, wv.z, wv.w};
            #pragma unroll
            for (int i = 0; i < 8; i++)
                #pragma unroll
                for (int j = 0; j < 4; j++)
                    acc[i][j] = __builtin_fmaf(a[i], w[j], acc[i][j]);
        }
        __syncthreads();
        int ke = k0 + 16;
        bool fold = (K == 512) ? (ke == 256)
                  : ((ke <= 1536 && (ke % 384) == 0) || ke == 1792);
        if (fold && ke < K) {
            #pragma unroll
            for (int i = 0; i < 8; i++)
                #pragma unroll
                for (int j = 0; j < 4; j++) {
                    cmem[i][j] = __fadd_rn(cmem[i][j], acc[i][j]);
                    acc[i][j] = 0.0f;
                }
        }
    }
    #pragma unroll
    for (int i = 0; i < 8; i++) {
        int r = row0 + ((i < 4) ? (tm * 4 + i) : (64 + tm * 4 + (i - 4)));
        #pragma unroll
        for (int j = 0; j < 4; j++) {
            int c = col0 + tn * 4 + j;
            if (c < N) {
                float v = __fadd_rn(cmem[i][j], acc[i][j]);
                if (flags & 1) v = __fadd_rn(v, bias[c]);
                if (flags & 2) v = fmaxf(v, 0.0f);
                C[(size_t)r * N + c] = v;
            }
        }
    }
}

// ---------------- attention scores v2: LDS-tiled, exact 4-acc chains --------
// Per (q,k): a_{d&3} += q[d]*k[d] ascending d (mul/add separate), then
// (a0+a1)+(a2+a3), *0.125f — identical to R9.
__global__ __launch_bounds__(256) void k_scores(const float* __restrict__ qkv,
                                                float* __restrict__ attnP, int b0) {
    __shared__ float Qs[64][64];   // [d][row]
    __shared__ float Ks[64][64];   // [d][row]
    int t = threadIdx.x;
    int bx = blockIdx.x;
    int kt = bx & 7, qt = (bx >> 3) & 7, h = (bx >> 6) & 7, bi = bx >> 9;
    int b = b0 + bi;
    {
        int r = t & 63, d0 = (t >> 6) * 16;
        const float* qp = qkv + (size_t)(b * 512 + qt * 64 + r) * 1536 + h * 64 + d0;
        const float* kp = qkv + (size_t)(b * 512 + kt * 64 + r) * 1536 + 512 + h * 64 + d0;
        #pragma unroll
        for (int m = 0; m < 4; m++) {
            float4 vq = *(const float4*)(qp + 4 * m);
            float4 vk = *(const float4*)(kp + 4 * m);
            Qs[d0 + 4 * m + 0][r] = vq.x; Qs[d0 + 4 * m + 1][r] = vq.y;
            Qs[d0 + 4 * m + 2][r] = vq.z; Qs[d0 + 4 * m + 3][r] = vq.w;
            Ks[d0 + 4 * m + 0][r] = vk.x; Ks[d0 + 4 * m + 1][r] = vk.y;
            Ks[d0 + 4 * m + 2][r] = vk.z; Ks[d0 + 4 * m + 3][r] = vk.w;
        }
    }
    __syncthreads();
    int tm = t & 15, tn = t >> 4;
    float acc[4][4][4];
    #pragma unroll
    for (int i = 0; i < 4; i++)
        #pragma unroll
        for (int j = 0; j < 4; j++)
            #pragma unroll
            for (int m = 0; m < 4; m++) acc[i][j][m] = 0.0f;
    #pragma unroll
    for (int d = 0; d < 64; d++) {
        float4 vq = *(const float4*)&Qs[d][tm * 4];
        float4 vk = *(const float4*)&Ks[d][tn * 4];
        float qa[4] = {vq.x, vq.y, vq.z, vq.w};
        float kb[4] = {vk.x, vk.y, vk.z, vk.w};
        const int m = d & 3;
        #pragma unroll
        for (int i = 0; i < 4; i++)
            #pragma unroll
            for (int j = 0; j < 4; j++)
                acc[i][j][m] = __fadd_rn(acc[i][j][m], __fmul_rn(qa[i], kb[j]));
    }
    size_t rb = ((size_t)(bi * 8 + h) * 512 + qt * 64);
    #pragma unroll
    for (int i = 0; i < 4; i++) {
        float4 o;
        o.x = __fmul_rn(__fadd_rn(__fadd_rn(acc[i][0][0], acc[i][0][1]), __fadd_rn(acc[i][0][2], acc[i][0][3])), 0.125f);
        o.y = __fmul_rn(__fadd_rn(__fadd_rn(acc[i][1][0], acc[i][1][1]), __fadd_rn(acc[i][1][2], acc[i][1][3])), 0.125f);
        o.z = __fmul_rn(__fadd_rn(__fadd_rn(acc[i][2][0], acc[i][2][1]), __fadd_rn(acc[i][2][2], acc[i][2][3])), 0.125f);
        o.w = __fmul_rn(__fadd_rn(__fadd_rn(acc[i][3][0], acc[i][3][1]), __fadd_rn(acc[i][3][2], acc[i][3][3])), 0.125f);
        *(float4*)&attnP[(rb + tm * 4 + i) * 512 + kt * 64 + tn * 4] = o;
    }
}

// ---------------- softmax (unchanged) ----------------
__global__ __launch_bounds__(256) void k_softmax(float* __restrict__ attnP) {
    __shared__ float ebuf[4][512];
    int wid = threadIdx.x >> 6, lane = threadIdx.x & 63;
    int row = blockIdx.x * 4 + wid;
    float* pr = attnP + (size_t)row * 512;
    float s[8], m = -INFINITY;
    for (int i = 0; i < 8; i++) { s[i] = pr[i * 64 + lane]; m = fmaxf(m, s[i]); }
    for (int off = 32; off; off >>= 1) m = fmaxf(m, __shfl_xor(m, off, 64));
    for (int i = 0; i < 8; i++)
        ebuf[wid][i * 64 + lane] = np_expf(__fsub_rn(s[i], m));
    __syncthreads();
    float sum = pairwise512(ebuf[wid], lane);
    for (int i = 0; i < 8; i++) pr[i * 64 + lane] = __fdiv_rn(ebuf[wid][i * 64 + lane], sum);
}

// ---------------- PV einsum (unchanged: sequential k, mul+add) --------------
__global__ __launch_bounds__(256) void k_pv(const float* __restrict__ attnP,
                                            const float* __restrict__ qkv,
                                            float* __restrict__ ctx, int b0) {
    __shared__ float at_s[64][65];
    __shared__ float v_s[64][65];
    int t = threadIdx.x;
    int bx = blockIdx.x;
    int qt = bx & 7, h = (bx >> 3) & 7, bi = bx >> 6;
    int b = b0 + bi;
    int tm = t & 15, tn = t >> 4;
    int lr = t >> 2, lc = (t & 3) * 16;
    float acc[4][4] = {};
    for (int c = 0; c < 8; c++) {
        const float* ar = attnP + ((size_t)(bi * 8 + h) * 512 + qt * 64 + lr) * 512 + c * 64 + lc;
        #pragma unroll
        for (int i = 0; i < 16; i++) at_s[lr][lc + i] = ar[i];
        const float* vr = qkv + (size_t)(b * 512 + c * 64 + lr) * 1536 + 1024 + h * 64 + lc;
        #pragma unroll
        for (int i = 0; i < 16; i++) v_s[lr][lc + i] = vr[i];
        __syncthreads();
        #pragma unroll
        for (int kk = 0; kk < 64; kk++) {
            float av[4], bv[4];
            #pragma unroll
            for (int i = 0; i < 4; i++) av[i] = at_s[tm + 16 * i][kk];
            #pragma unroll
            for (int j = 0; j < 4; j++) bv[j] = v_s[kk][tn + 16 * j];
            #pragma unroll
            for (int i = 0; i < 4; i++)
                #pragma unroll
                for (int j = 0; j < 4; j++)
                    acc[i][j] = __fadd_rn(acc[i][j], __fmul_rn(av[i], bv[j]));
        }
        __syncthreads();
    }
    #pragma unroll
    for (int i = 0; i < 4; i++)
        #pragma unroll
        for (int j = 0; j < 4; j++) {
            int q = qt * 64 + tm + 16 * i, dh = tn + 16 * j;
            ctx[(size_t)(b * 512 + q) * 512 + h * 64 + dh] = acc[i][j];
        }
}

// ---------------- residual + LayerNorm (unchanged) ----------------
__global__ __launch_bounds__(256) void k_addln32(const float* __restrict__ xin,
                                                 const float* __restrict__ yin,
                                                 const float* __restrict__ ob,
                                                 const float* __restrict__ sc,
                                                 const float* __restrict__ bi,
                                                 float* __restrict__ xout) {
    __shared__ float buf[512];
    __shared__ float d2[512];
    __shared__ float stats[2];
    int row = blockIdx.x, t = threadIdx.x;
    const float* xr = xin + (size_t)row * 512;
    const float* yr = yin + (size_t)row * 512;
    float v0 = __fadd_rn(xr[t], yr[t]);
    float v1 = __fadd_rn(xr[t + 256], yr[t + 256]);
    if (ob) { v0 = __fadd_rn(v0, ob[t]); v1 = __fadd_rn(v1, ob[t + 256]); }
    buf[t] = v0; buf[t + 256] = v1;
    __syncthreads();
    int lane = t & 63;
    if (t < 64) {
        float s = pairwise512(buf, lane);
        if (lane == 0) stats[0] = __fdiv_rn(s, 512.0f);
    }
    __syncthreads();
    float mean = stats[0];
    float d0 = __fsub_rn(v0, mean), d1 = __fsub_rn(v1, mean);
    d2[t] = __fmul_rn(d0, d0); d2[t + 256] = __fmul_rn(d1, d1);
    __syncthreads();
    if (t < 64) {
        float s = pairwise512(d2, lane);
        if (lane == 0) {
            float var = __fdiv_rn(s, 512.0f);
            stats[1] = __fdiv_rn(1.0f, __fsqrt_rn(__fadd_rn(var, 1e-5f)));
        }
    }
    __syncthreads();
    float inv = stats[1];
    xout[(size_t)row * 512 + t]       = __fadd_rn(__fmul_rn(__fmul_rn(d0, inv), sc[t]), bi[t]);
    xout[(size_t)row * 512 + t + 256] = __fadd_rn(__fmul_rn(__fmul_rn(d1, inv), sc[t + 256]), bi[t + 256]);
}

// ---------------- sdot v2: identical chains, LDS double-buffered ------------
// Chain c (lane c<32): acc = fma(x[i],x[i],acc) for i = c, c+32, ... ascending
// — identical sequence to R9; memory now staged via LDS by all 256 threads.
__global__ __launch_bounds__(256) void k_sdot(const float* __restrict__ x,
                                              float* __restrict__ den) {
    __shared__ float sbuf[2][4096];
    int t = threadIdx.x;
    #pragma unroll
    for (int q = 0; q < 4; q++)
        *(float4*)&sbuf[0][q * 1024 + t * 4] = *(const float4*)&x[q * 1024 + t * 4];
    __syncthreads();
    float acc = 0.0f;
    for (int ch = 0; ch < 1024; ch++) {
        int p = ch & 1;
        if (ch + 1 < 1024) {
            const float* src = x + (size_t)(ch + 1) * 4096;
            #pragma unroll
            for (int q = 0; q < 4; q++)
                *(float4*)&sbuf[p ^ 1][q * 1024 + t * 4] = *(const float4*)&src[q * 1024 + t * 4];
        }
        if (t < 32) {
            const float* bp = sbuf[p];
            #pragma unroll 16
            for (int jj = 0; jj < 128; jj++) {
                float v = bp[jj * 32 + t];
                acc = __builtin_fmaf(v, v, acc);
            }
        }
        __syncthreads();
    }
    acc = __fadd_rn(acc, __shfl_xor(acc, 8, 64));
    acc = __fadd_rn(acc, __shfl_xor(acc, 16, 64));
    acc = __fadd_rn(acc, __shfl_xor(acc, 4, 64));
    acc = __fadd_rn(acc, __shfl_xor(acc, 1, 64));
    acc = __fadd_rn(acc, __shfl_xor(acc, 2, 64));
    if (t == 0) den[0] = __fadd_rn(__fsqrt_rn(acc), 1e-8f);
}

// ---------------- quantile machinery (unchanged) ----------------
__global__ void k_qinit(unsigned long long* state, unsigned int* hist) {
    int t = threadIdx.x;
    hist[t] = 0;
    if (t == 0) { state[0] = 0; state[1] = R0Q; state[2] = 0; state[3] = ~0ULL; }
}

__global__ __launch_bounds__(256) void k_gkeys32(const float* __restrict__ x,
                                                 const float* __restrict__ den_p,
                                                 unsigned int* __restrict__ keys) {
    int i = blockIdx.x * 256 + threadIdx.x;
    float g = __fmul_rn(__fdiv_rn(x[i], den_p[0]), 2048.0f);
    keys[i] = __float_as_uint(fabsf(g));
}

__global__ __launch_bounds__(256) void k_hist32(const unsigned int* __restrict__ keys,
                                                const unsigned long long* __restrict__ state,
                                                unsigned int* __restrict__ hist, int shift) {
    __shared__ unsigned int h[256];
    h[threadIdx.x] = 0;
    __syncthreads();
    unsigned int pref = (unsigned int)state[0];
    for (size_t i = (size_t)blockIdx.x * 256 + threadIdx.x; i < (size_t)NTOT; i += 262144) {
        unsigned int k = keys[i];
        if (shift == 24 || (k >> (shift + 8)) == pref)
            atomicAdd(&h[(k >> shift) & 255u], 1u);
    }
    __syncthreads();
    atomicAdd(&hist[threadIdx.x], h[threadIdx.x]);
}

__global__ void k_scan32(unsigned long long* state, unsigned int* hist) {
    if (threadIdx.x == 0) {
        unsigned long long r = state[1], cum = 0;
        int b = 0;
        for (; b < 256; b++) {
            unsigned long long c = hist[b];
            if (cum + c > r) break;
            cum += c;
        }
        state[0] = (state[0] << 8) | (unsigned long long)b;
        state[1] = r - cum;
    }
    __syncthreads();
    hist[threadIdx.x] = 0;
}

__global__ __launch_bounds__(256) void k_fixcnt32(const unsigned int* __restrict__ keys,
                                                  unsigned long long* __restrict__ state) {
    __shared__ unsigned long long lc[4];
    __shared__ unsigned int lm[4];
    unsigned int v0 = (unsigned int)state[0];
    unsigned long long cnt = 0;
    unsigned int mn = 0xFFFFFFFFu;
    for (size_t i = (size_t)blockIdx.x * 256 + threadIdx.x; i < (size_t)NTOT; i += 262144) {
        unsigned int k = keys[i];
        if (k <= v0) cnt++;
        else if (k < mn) mn = k;
    }
    for (int off = 32; off; off >>= 1) {
        cnt += __shfl_xor(cnt, off, 64);
        unsigned int o = __shfl_xor(mn, off, 64);
        if (o < mn) mn = o;
    }
    int wid = threadIdx.x >> 6, ln = threadIdx.x & 63;
    if (ln == 0) { lc[wid] = cnt; lm[wid] = mn; }
    __syncthreads();
    if (threadIdx.x == 0) {
        unsigned long long c = lc[0] + lc[1] + lc[2] + lc[3];
        unsigned int m2 = lm[0];
        if (lm[1] < m2) m2 = lm[1];
        if (lm[2] < m2) m2 = lm[2];
        if (lm[3] < m2) m2 = lm[3];
        atomicAdd(&state[2], c);
        atomicMin(&state[3], (unsigned long long)m2);
    }
}

__global__ void k_thr32(const unsigned long long* __restrict__ state,
                        float* __restrict__ thr_p) {
    if (threadIdx.x == 0 && blockIdx.x == 0) {
        float a = __uint_as_float((unsigned int)state[0]);
        float b = (state[2] > R0Q + 1) ? a : __uint_as_float((unsigned int)state[3]);
        thr_p[0] = __fadd_rn(a, __fmul_rn(__fsub_rn(b, a), 0.25f));
    }
}

__global__ __launch_bounds__(256) void k_damp32(float* __restrict__ x,
                                                const float* __restrict__ den_p,
                                                const float* __restrict__ thr_p,
                                                float c1, float c2) {
    int i = blockIdx.x * 256 + threadIdx.x;
    float g = __fmul_rn(__fdiv_rn(x[i], den_p[0]), 2048.0f);
    float v = (fabsf(g) > thr_p[0]) ? g : 0.0f;
    x[i] = __fmul_rn(__fmul_rn(v, c1), c2);
}

// ---------------- host orchestration ----------------------------------------
extern "C" void kernel_launch(void* const* d_in, const int* in_sizes, int n_in,
                              void* d_out, int out_size, void* d_ws, size_t ws_size,
                              hipStream_t stream) {
    const int*   src     = (const int*)d_in[0];
    const float* emb     = (const float*)d_in[1];
    const float* pos     = (const float*)d_in[2];
    const float* qkv_w   = (const float*)d_in[3];
    const float* qkv_b   = (const float*)d_in[4];
    const float* attn_ow = (const float*)d_in[5];
    const float* attn_ob = (const float*)d_in[6];
    const float* ln1_s   = (const float*)d_in[7];
    const float* ln1_b   = (const float*)d_in[8];
    const float* ln2_s   = (const float*)d_in[9];
    const float* ln2_b   = (const float*)d_in[10];
    const float* ff1_w   = (const float*)d_in[11];
    const float* ff1_b   = (const float*)d_in[12];
    const float* ff2_w   = (const float*)d_in[13];
    const float* ff2_b   = (const float*)d_in[14];
    const float* head_w  = (const float*)d_in[15];
    const float* head_b  = (const float*)d_in[16];

    char* ws = (char*)d_ws;
    float* x    = (float*)(ws + 0);
    float* qkv  = (float*)(ws + 16777216ULL);
    float* ffh  = (float*)(ws + 67108864ULL);
    float* y    = (float*)(ws + 134217728ULL);
    float* ctx  = (float*)(ws + 150994944ULL);
    float* attnP= (float*)(ws + 167772160ULL);
    unsigned int* keys = (unsigned int*)ctx;            // aliases ctx (dead by then)
    float*  den  = (float*)(ws + 184557568ULL);
    float*  thr  = (float*)(ws + 184557572ULL);
    unsigned int* hist = (unsigned int*)(ws + 184561664ULL);
    unsigned long long* state = (unsigned long long*)(ws + 184565760ULL);

    float sc_emb = (float)sqrt(512.0);                 // np.sqrt(D).astype(f32)
    float c1 = (float)pow(0.99, 1.0 / 6.0);            // np.float32(DAMP**(1/L))

    k_embed32<<<16384, 256, 0, stream>>>(src, emb, pos, x, sc_emb);

    for (int l = 0; l < LL; l++) {
        // qkv = x @ qkv_w^T + qkv_b   [8192,1536]
        k_gemm2<<<dim3(24, 64), 256, 0, stream>>>(
            x, qkv_w + (size_t)l * 1536 * 512, qkv_b + (size_t)l * 1536, qkv, 1536, 512, 1);
        // attention, 2 batches per phase
        for (int ph = 0; ph < 8; ph++) {
            int b0 = ph * 2;
            k_scores<<<1024, 256, 0, stream>>>(qkv, attnP, b0);
            k_softmax<<<2048, 256, 0, stream>>>(attnP);
            k_pv<<<128, 256, 0, stream>>>(attnP, qkv, ctx, b0);
        }
        // proj (raw matmul; ob added in addln to match ((x + mm) + ob) order)
        k_gemm2<<<dim3(8, 64), 256, 0, stream>>>(
            ctx, attn_ow + (size_t)l * 512 * 512, nullptr, y, 512, 512, 0);
        k_addln32<<<8192, 256, 0, stream>>>(x, y, attn_ob + (size_t)l * 512,
                                            ln1_s + (size_t)l * 512, ln1_b + (size_t)l * 512, x);
        // FF
        k_gemm2<<<dim3(32, 64), 256, 0, stream>>>(
            x, ff1_w + (size_t)l * 2048 * 512, ff1_b + (size_t)l * 2048, ffh, 2048, 512, 3);
        k_gemm2<<<dim3(8, 64), 256, 0, stream>>>(
            ffh, ff2_w + (size_t)l * 512 * 2048, ff2_b + (size_t)l * 512, y, 512, 2048, 1);
        k_addln32<<<8192, 256, 0, stream>>>(x, y, nullptr,
                                            ln2_s + (size_t)l * 512, ln2_b + (size_t)l * 512, x);
        // resonance: exact sdot norm, radix-select quantile, threshold+damp
        k_sdot<<<1, 256, 0, stream>>>(x, den);
        k_qinit<<<1, 256, 0, stream>>>(state, hist);
        k_gkeys32<<<16384, 256, 0, stream>>>(x, den, keys);
        for (int p = 0; p < 4; p++) {
            k_hist32<<<1024, 256, 0, stream>>>(keys, state, hist, 24 - 8 * p);
            k_scan32<<<1, 256, 0, stream>>>(state, hist);
        }
        k_fixcnt32<<<1024, 256, 0, stream>>>(keys, state);
        k_thr32<<<1, 1, 0, stream>>>(state, thr);
        float c2 = (float)pow(0.99, (double)l / 6.0);  // np.float32(DAMP**(i/L))
        k_damp32<<<16384, 256, 0, stream>>>(x, den, thr, c1, c2);
    }

    // head: out = x @ head_w^T + head_b   [8192,10000]
    k_gemm2<<<dim3(157, 64), 256, 0, stream>>>(
        x, head_w, head_b, (float*)d_out, 10000, 512, 1);
}